// Round 15
// baseline (320.926 us; speedup 1.0000x reference)
//
#include <hip/hip_runtime.h>

typedef __attribute__((ext_vector_type(8))) short short8;
typedef __attribute__((ext_vector_type(4))) float f32x4;

constexpr int T_STEPS = 32;
constexpr int BATCH   = 32;
constexpr int DG      = 256;
constexpr int DH      = 512;
constexpr int NHIST   = 31;
constexpr float LAMBDA_ = 0.95f;
constexpr float ETA_    = 0.5f;
constexpr float EPS_    = 1e-5f;

__device__ __forceinline__ uint bf16cvt(float f) {
  uint u = __float_as_uint(f);
  return (u + 0x7FFFu + ((u >> 16) & 1u)) >> 16;
}
__device__ __forceinline__ uint pack2(float a, float b) {
  return bf16cvt(a) | (bf16cvt(b) << 16);
}
__device__ __forceinline__ float bf2f(ushort u) {
  return __uint_as_float(((uint)u) << 16);
}

// Raw barrier: does NOT drain vmcnt (so prestaged global_load_lds stay in
// flight across it) but DOES drain LDS ops for cross-wave visibility.
__device__ __forceinline__ void block_barrier() {
  __builtin_amdgcn_sched_barrier(0);
  asm volatile("s_waitcnt lgkmcnt(0)" ::: "memory");
  __builtin_amdgcn_s_barrier();
  __builtin_amdgcn_sched_barrier(0);
}

// pack: W_h fp32 -> bf16 MFMA A-fragment layout.
// Wp[(mt*16+kk)*64 + lane] = uint4 of 8 bf16 =
//   W[mt*16 + (lane&15)][kk*32 + (lane>>4)*8 .. +8)
__global__ __launch_bounds__(512) void pack_kernel(
    const float* __restrict__ Wh, uint4* __restrict__ Wp) {
  const int f  = blockIdx.x * 512 + threadIdx.x;   // 0..32767
  const int lf = f & 63;
  const int kk = (f >> 6) & 15;
  const int mt = f >> 10;
  const int r  = mt * 16 + (lf & 15);
  const int k0 = kk * 32 + (lf >> 4) * 8;
  const float4 a = *reinterpret_cast<const float4*>(Wh + (size_t)r * DH + k0);
  const float4 b = *reinterpret_cast<const float4*>(Wh + (size_t)r * DH + k0 + 4);
  Wp[f] = make_uint4(pack2(a.x, a.y), pack2(a.z, a.w),
                     pack2(b.x, b.y), pack2(b.z, b.w));
}

// Serial recurrence: 32 self-contained blocks x 512 threads, one batch each.
// - Phase 1: W streamed via global_load_lds 2-slot ring, counted vmcnt,
//   NEXT step's first 2 columns prestaged across phases 2-4 (raw barriers).
// - dots  : 31x512 matvec via MFMA on fragment-layout history (K-split/wave).
// - Ah    : scalar u16 gather from the same fragment array.
// - ZG    : bf16 in LDS, written by the MFMA prologue.
__global__ __launch_bounds__(512, 2) void rnn_kernel(
    const uint4* __restrict__ Wp, const float* __restrict__ z,
    const float* __restrict__ Wg, const float* __restrict__ bh,
    const float* __restrict__ g, const float* __restrict__ be,
    float* __restrict__ out) {
  __shared__ uint4  stage[8][2][4][64];     // 64 KB: wave-private W ring
  __shared__ uint4  hist_frag[2 * 16 * 64]; // 32 KB: history, A-frag layout
  __shared__ ushort zg_bf[T_STEPS][DH];     // 32 KB: ZG rows (bf16)
  __shared__ float  part[DH];
  __shared__ float  h_s[DH];
  __shared__ ushort hbf[DH];
  __shared__ float  pdots[8][32];
  __shared__ float  red1[8], red2[8];
  __shared__ float  cc[32];
  __shared__ float  lam_pow[NHIST];

  const int tid  = threadIdx.x;            // 0..511
  const int lane = tid & 63;
  const int wave = tid >> 6;               // 0..7
  const int c    = lane & 15;              // mfma col
  const int gq   = lane >> 4;              // mfma k-group / row-quad
  const int b    = blockIdx.x;             // batch == block
  const int r    = tid;                    // owned row

  if (tid == 0) {
    float p = 1.f;
    for (int k = 0; k < NHIST; ++k) { lam_pow[k] = p; p *= LAMBDA_; }
  }
  // zero history fragments (so sp >= t reads are defined)
  for (int i = tid; i < 2 * 16 * 64; i += 512)
    hist_frag[i] = make_uint4(0u, 0u, 0u, 0u);

  // async stage of one kk-column (4 tiles) into stage[wave][slot]
  auto STAGE = [&](int kk, int slot) {
#pragma unroll
    for (int mt4 = 0; mt4 < 4; ++mt4) {
      const uint4* gsrc = Wp + (size_t)((wave * 4 + mt4) * 16 + kk) * 64 + lane;
      __builtin_amdgcn_global_load_lds(
          (const __attribute__((address_space(1))) uint*)gsrc,
          (__attribute__((address_space(3))) uint*)&stage[wave][slot][mt4][0],
          16, 0, 0);
    }
  };

  // ---- Prologue: zg_bf[t][:] = bf16(z_b @ Wg^T) (MFMA; cols = t) ----
#pragma unroll
  for (int mt4 = 0; mt4 < 4; ++mt4) {
    const int mt = wave * 4 + mt4;          // 32 M-tiles over DH=512
    f32x4 acc0 = {0.f,0.f,0.f,0.f}, acc1 = {0.f,0.f,0.f,0.f};
#pragma unroll
    for (int kk = 0; kk < 8; ++kk) {        // K = 256
      const int k0 = kk * 32 + gq * 8;
      const float4 a  = *reinterpret_cast<const float4*>(Wg + (size_t)(mt*16 + c) * DG + k0);
      const float4 a2 = *reinterpret_cast<const float4*>(Wg + (size_t)(mt*16 + c) * DG + k0 + 4);
      const uint4 afu = make_uint4(pack2(a.x,a.y), pack2(a.z,a.w),
                                   pack2(a2.x,a2.y), pack2(a2.z,a2.w));
      const float* zb0 = z + ((size_t)c        * BATCH + b) * DG + k0;  // t = c
      const float* zb1 = z + ((size_t)(16 + c) * BATCH + b) * DG + k0;  // t = 16+c
      const float4 b00 = *reinterpret_cast<const float4*>(zb0);
      const float4 b01 = *reinterpret_cast<const float4*>(zb0 + 4);
      const float4 b10 = *reinterpret_cast<const float4*>(zb1);
      const float4 b11 = *reinterpret_cast<const float4*>(zb1 + 4);
      const uint4 bf0 = make_uint4(pack2(b00.x,b00.y), pack2(b00.z,b00.w),
                                   pack2(b01.x,b01.y), pack2(b01.z,b01.w));
      const uint4 bf1 = make_uint4(pack2(b10.x,b10.y), pack2(b10.z,b10.w),
                                   pack2(b11.x,b11.y), pack2(b11.z,b11.w));
      acc0 = __builtin_amdgcn_mfma_f32_16x16x32_bf16(
          __builtin_bit_cast(short8, afu), __builtin_bit_cast(short8, bf0), acc0, 0,0,0);
      acc1 = __builtin_amdgcn_mfma_f32_16x16x32_bf16(
          __builtin_bit_cast(short8, afu), __builtin_bit_cast(short8, bf1), acc1, 0,0,0);
    }
    // D: col=lane&15 -> t, rows mt*16 + gq*4 + 0..3
    *reinterpret_cast<uint2*>(&zg_bf[c][mt*16 + gq*4]) =
        make_uint2(pack2(acc0.x, acc0.y), pack2(acc0.z, acc0.w));
    *reinterpret_cast<uint2*>(&zg_bf[16 + c][mt*16 + gq*4]) =
        make_uint2(pack2(acc1.x, acc1.y), pack2(acc1.z, acc1.w));
  }
  const float bh_r = bh[r], g_r = g[r], be_r = be[r];
  block_barrier();

  STAGE(0, 0); STAGE(1, 1);   // prestage for t=1 (stays in flight over t=0)

  // LayerNorm+ReLU over 512 thread-held scalars; 2 raw barriers.
  auto ln = [&](float x) -> float {
    float s1 = x, s2 = x * x;
#pragma unroll
    for (int off = 32; off; off >>= 1) {
      s1 += __shfl_xor(s1, off, 64);
      s2 += __shfl_xor(s2, off, 64);
    }
    if (lane == 0) { red1[wave] = s1; red2[wave] = s2; }
    block_barrier();
    float a = 0.f, q = 0.f;
#pragma unroll
    for (int w2 = 0; w2 < 8; ++w2) { a += red1[w2]; q += red2[w2]; }
    const float mu = a * (1.f / DH);
    const float rs = rsqrtf(q * (1.f / DH) - mu * mu + EPS_);
    const float hv2 = fmaxf((x - mu) * rs * g_r + be_r, 0.f);
    h_s[r] = hv2;
    hbf[r] = (ushort)bf16cvt(hv2);
    block_barrier();
    return hv2;
  };

  float hv = 0.f;
  for (int t = 0; t < T_STEPS; ++t) {
    float xb;
    if (t == 0) {
      xb = bf2f(zg_bf[0][r]) + bh_r;       // h==0: hb = zg
    } else {
      // Phase 1: hb = Wh.h via MFMA, 2-slot LDS ring, counted vmcnt.
      f32x4 acc[4] = {{0.f,0.f,0.f,0.f},{0.f,0.f,0.f,0.f},
                      {0.f,0.f,0.f,0.f},{0.f,0.f,0.f,0.f}};
#pragma unroll
      for (int kk = 0; kk < 16; ++kk) {
        const int slot = kk & 1;
        if (kk < 15) { asm volatile("s_waitcnt vmcnt(4)" ::: "memory"); }
        else         { asm volatile("s_waitcnt vmcnt(0)" ::: "memory"); }
        __builtin_amdgcn_sched_barrier(0);
        const uint4 a0 = stage[wave][slot][0][lane];
        const uint4 a1 = stage[wave][slot][1][lane];
        const uint4 a2 = stage[wave][slot][2][lane];
        const uint4 a3 = stage[wave][slot][3][lane];
        uint4 bvu = {0u,0u,0u,0u};
        if (c == 0)
          bvu = *reinterpret_cast<const uint4*>(&hbf[kk*32 + gq*8]);
        const short8 bv = __builtin_bit_cast(short8, bvu);
        acc[0] = __builtin_amdgcn_mfma_f32_16x16x32_bf16(
            __builtin_bit_cast(short8, a0), bv, acc[0], 0,0,0);
        acc[1] = __builtin_amdgcn_mfma_f32_16x16x32_bf16(
            __builtin_bit_cast(short8, a1), bv, acc[1], 0,0,0);
        acc[2] = __builtin_amdgcn_mfma_f32_16x16x32_bf16(
            __builtin_bit_cast(short8, a2), bv, acc[2], 0,0,0);
        acc[3] = __builtin_amdgcn_mfma_f32_16x16x32_bf16(
            __builtin_bit_cast(short8, a3), bv, acc[3], 0,0,0);
        if (kk < 14) STAGE(kk + 2, slot);   // rolling refill
      }
      // prestage NEXT step's first 2 columns; they drain during phases 2-4
      if (t < T_STEPS - 1) { STAGE(0, 0); STAGE(1, 1); }
      if (c == 0) {
#pragma unroll
        for (int mt4 = 0; mt4 < 4; ++mt4)
          *reinterpret_cast<f32x4*>(&part[(wave*4 + mt4)*16 + gq*4]) = acc[mt4];
      }
      block_barrier();                                   // B1 (no vmcnt drain)
      xb = part[r] + bf2f(zg_bf[t][r]) + bh_r;
    }

    // Phase 2: h = relu(LN(hb))
    hv = ln(xb);

    // Phase 3: S_LOOP=2 fast-weight reads (A==0 at t=0 -> skip)
    if (t > 0) {
      for (int s = 0; s < 2; ++s) {
        // dots via MFMA: D[sp] = hist . h, K split 64/wave (kk0,kk1)
        const int kk0 = 2 * wave, kk1 = kk0 + 1;
        uint4 b0u = {0u,0u,0u,0u}, b1u = {0u,0u,0u,0u};
        if (c == 0) {
          b0u = *reinterpret_cast<const uint4*>(&hbf[kk0*32 + gq*8]);
          b1u = *reinterpret_cast<const uint4*>(&hbf[kk1*32 + gq*8]);
        }
        const short8 b0 = __builtin_bit_cast(short8, b0u);
        const short8 b1 = __builtin_bit_cast(short8, b1u);
        f32x4 d0 = {0.f,0.f,0.f,0.f}, d1 = {0.f,0.f,0.f,0.f};
        d0 = __builtin_amdgcn_mfma_f32_16x16x32_bf16(
            __builtin_bit_cast(short8, hist_frag[kk0*64 + lane]), b0, d0, 0,0,0);
        d0 = __builtin_amdgcn_mfma_f32_16x16x32_bf16(
            __builtin_bit_cast(short8, hist_frag[kk1*64 + lane]), b1, d0, 0,0,0);
        d1 = __builtin_amdgcn_mfma_f32_16x16x32_bf16(
            __builtin_bit_cast(short8, hist_frag[(16+kk0)*64 + lane]), b0, d1, 0,0,0);
        d1 = __builtin_amdgcn_mfma_f32_16x16x32_bf16(
            __builtin_bit_cast(short8, hist_frag[(16+kk1)*64 + lane]), b1, d1, 0,0,0);
        if (c == 0) {
          *reinterpret_cast<f32x4*>(&pdots[wave][gq*4])      = d0;
          *reinterpret_cast<f32x4*>(&pdots[wave][16 + gq*4]) = d1;
        }
        block_barrier();
        if (tid < 32) {
          float d = 0.f;
#pragma unroll
          for (int w = 0; w < 8; ++w) d += pdots[w][tid];
          cc[tid] = (tid < t) ? ETA_ * lam_pow[t - 1 - tid] * d : 0.f;
        }
        block_barrier();
        // Ah[r] = sum_sp cc[sp] * hist[sp][r]  (u16 gather from fragments)
        float ah = 0.f;
        {
          const ushort* hf = reinterpret_cast<const ushort*>(hist_frag);
          const int base_r = ((r >> 5) * 64 + ((r >> 3) & 3) * 16) * 8 + (r & 7);
#pragma unroll
          for (int sp = 0; sp < NHIST; ++sp)
            ah = fmaf(cc[sp], bf2f(hf[base_r + (sp & 15) * 8 + (sp >> 4) * 8192]), ah);
        }
        hv = ln(xb + ah);
      }
    }

    // Phase 4: hist[t] := h  (element (sp=t, r) in fragment layout)
    if (t < T_STEPS - 1) {
      ushort* hf = reinterpret_cast<ushort*>(hist_frag);
      const int idx = (((t >> 4) * 16 + (r >> 5)) * 64 +
                       ((r >> 3) & 3) * 16 + (t & 15)) * 8 + (r & 7);
      hf[idx] = (ushort)bf16cvt(hv);
    }
  }

  out[(size_t)b * DH + r] = hv;
}

extern "C" void kernel_launch(void* const* d_in, const int* in_sizes, int n_in,
                              void* d_out, int out_size, void* d_ws, size_t ws_size,
                              hipStream_t stream) {
  const float* z     = (const float*)d_in[0];  // [T,B,DG]
  const float* W_h   = (const float*)d_in[1];  // [DH,DH]
  const float* W_g   = (const float*)d_in[2];  // [DH,DG]
  const float* b_h   = (const float*)d_in[3];  // [DH]
  const float* gamma = (const float*)d_in[4];  // [DH]
  const float* beta  = (const float*)d_in[5];  // [DH]
  float* out = (float*)d_out;                  // [B,DH]

  uint4* Wp = (uint4*)d_ws;                    // 512 KB packed W_h

  pack_kernel<<<dim3(64), dim3(512), 0, stream>>>(W_h, Wp);
  rnn_kernel<<<dim3(BATCH), dim3(512), 0, stream>>>(Wp, z, W_g, b_h,
                                                    gamma, beta, out);
}

// Round 16
// 290.204 us; speedup vs baseline: 1.1059x; 1.1059x over previous
//
#include <hip/hip_runtime.h>

typedef __attribute__((ext_vector_type(8))) short short8;
typedef __attribute__((ext_vector_type(4))) float f32x4;

constexpr int T_STEPS = 32;
constexpr int BATCH   = 32;
constexpr int DG      = 256;
constexpr int DH      = 512;
constexpr int NHIST   = 31;
constexpr int LDA     = 544;    // padded fp32 area row (words)
constexpr int LDT     = 40;     // histT row (ushorts): 80 B, 16B-aligned
constexpr float LAMBDA_ = 0.95f;
constexpr float ETA_    = 0.5f;
constexpr float EPS_    = 1e-5f;

__device__ __forceinline__ uint bf16cvt(float f) {
  uint u = __float_as_uint(f);
  return (u + 0x7FFFu + ((u >> 16) & 1u)) >> 16;
}
__device__ __forceinline__ uint pack2(float a, float b) {
  return bf16cvt(a) | (bf16cvt(b) << 16);
}

// pack: W_h fp32 -> bf16 MFMA A-fragment layout.
// Wp[(mt*16+kk)*64 + lane] = uint4 of 8 bf16 =
//   W[mt*16 + (lane&15)][kk*32 + (lane>>4)*8 .. +8)
__global__ __launch_bounds__(512) void pack_kernel(
    const float* __restrict__ Wh, uint4* __restrict__ Wp) {
  const int f  = blockIdx.x * 512 + threadIdx.x;   // 0..32767
  const int lf = f & 63;
  const int kk = (f >> 6) & 15;
  const int mt = f >> 10;
  const int r  = mt * 16 + (lf & 15);
  const int k0 = kk * 32 + (lf >> 4) * 8;
  const float4 a = *reinterpret_cast<const float4*>(Wh + (size_t)r * DH + k0);
  const float4 b = *reinterpret_cast<const float4*>(Wh + (size_t)r * DH + k0 + 4);
  Wp[f] = make_uint4(pack2(a.x, a.y), pack2(a.z, a.w),
                     pack2(b.x, b.y), pack2(b.z, b.w));
}

// Serial recurrence: 32 self-contained blocks x 512 threads, one batch each.
// Round-13 structure, phase 1 fixed: B-fragments (hbf LDS reads) hoisted out
// of the K-loop in two 8-kk batches, so the inner loop is pure
// {global A-load -> MFMA} — no per-iteration lgkmcnt chained into the vmcnt
// ladder. The dead wfr "resident" prologue (rematerialized by the compiler,
// rounds 10-13) is deleted.
__global__ __launch_bounds__(512, 2) void rnn_kernel(
    const uint4* __restrict__ Wp, const float* __restrict__ z,
    const float* __restrict__ Wg, const float* __restrict__ bh,
    const float* __restrict__ g, const float* __restrict__ be,
    float* __restrict__ out) {
  __shared__ float  area[T_STEPS * LDA];     // ZG[t] -> hist[t]  (~70 KB)
  __shared__ ushort histT[DH][LDT];          // bf16 history, transposed (40 KB)
  __shared__ float  part[DH];
  __shared__ float  h_s[DH];
  __shared__ ushort hbf[DH];
  __shared__ float  red1[8], red2[8];
  __shared__ float  cc[NHIST + 1];
  __shared__ float  lam_pow[NHIST];

  const int tid  = threadIdx.x;            // 0..511
  const int lane = tid & 63;
  const int wave = tid >> 6;               // 0..7
  const int c    = lane & 15;              // mfma col
  const int gq   = lane >> 4;              // mfma k-group / row-quad
  const int b    = blockIdx.x;             // batch == block
  const int r    = tid;                    // owned row

  if (tid == 0) {
    float p = 1.f;
    for (int k = 0; k < NHIST; ++k) { lam_pow[k] = p; p *= LAMBDA_; }
  }
  if (tid < NHIST + 1) cc[tid] = 0.f;      // slots >= t stay 0 -> no Ah guards
  {                                         // zero own histT row (NaN guard)
    uint4 zz = make_uint4(0u, 0u, 0u, 0u);
#pragma unroll
    for (int i = 0; i < 5; ++i)
      reinterpret_cast<uint4*>(&histT[r][0])[i] = zz;
  }

  // ---- Prologue: area[t][:] = z_b @ Wg^T (MFMA bf16; cols = t, 2 halves) ----
#pragma unroll
  for (int mt4 = 0; mt4 < 4; ++mt4) {
    const int mt = wave * 4 + mt4;          // 32 M-tiles over DH=512
    f32x4 acc0 = {0.f,0.f,0.f,0.f}, acc1 = {0.f,0.f,0.f,0.f};
#pragma unroll
    for (int kk = 0; kk < 8; ++kk) {        // K = 256
      const int k0 = kk * 32 + gq * 8;
      const float4 a  = *reinterpret_cast<const float4*>(Wg + (size_t)(mt*16 + c) * DG + k0);
      const float4 a2 = *reinterpret_cast<const float4*>(Wg + (size_t)(mt*16 + c) * DG + k0 + 4);
      const uint4 afu = make_uint4(pack2(a.x,a.y), pack2(a.z,a.w),
                                   pack2(a2.x,a2.y), pack2(a2.z,a2.w));
      const float* zb0 = z + ((size_t)c        * BATCH + b) * DG + k0;  // t = c
      const float* zb1 = z + ((size_t)(16 + c) * BATCH + b) * DG + k0;  // t = 16+c
      const float4 b00 = *reinterpret_cast<const float4*>(zb0);
      const float4 b01 = *reinterpret_cast<const float4*>(zb0 + 4);
      const float4 b10 = *reinterpret_cast<const float4*>(zb1);
      const float4 b11 = *reinterpret_cast<const float4*>(zb1 + 4);
      const uint4 bf0 = make_uint4(pack2(b00.x,b00.y), pack2(b00.z,b00.w),
                                   pack2(b01.x,b01.y), pack2(b01.z,b01.w));
      const uint4 bf1 = make_uint4(pack2(b10.x,b10.y), pack2(b10.z,b10.w),
                                   pack2(b11.x,b11.y), pack2(b11.z,b11.w));
      acc0 = __builtin_amdgcn_mfma_f32_16x16x32_bf16(
          __builtin_bit_cast(short8, afu), __builtin_bit_cast(short8, bf0), acc0, 0,0,0);
      acc1 = __builtin_amdgcn_mfma_f32_16x16x32_bf16(
          __builtin_bit_cast(short8, afu), __builtin_bit_cast(short8, bf1), acc1, 0,0,0);
    }
    // D: col=lane&15 -> t, rows mt*16 + gq*4 + 0..3
    *reinterpret_cast<f32x4*>(&area[(size_t)c        * LDA + mt*16 + gq*4]) = acc0;
    *reinterpret_cast<f32x4*>(&area[(size_t)(16 + c) * LDA + mt*16 + gq*4]) = acc1;
  }
  __syncthreads();

  const float bh_r = bh[r], g_r = g[r], be_r = be[r];

  // LayerNorm+ReLU over 512 thread-held scalars; 2 barriers; writes h_s+hbf.
  auto ln = [&](float x) -> float {
    float s1 = x, s2 = x * x;
#pragma unroll
    for (int off = 32; off; off >>= 1) {
      s1 += __shfl_xor(s1, off, 64);
      s2 += __shfl_xor(s2, off, 64);
    }
    if (lane == 0) { red1[wave] = s1; red2[wave] = s2; }
    __syncthreads();
    float a = 0.f, q = 0.f;
#pragma unroll
    for (int w2 = 0; w2 < 8; ++w2) { a += red1[w2]; q += red2[w2]; }
    const float mu = a * (1.f / DH);
    const float rs = rsqrtf(q * (1.f / DH) - mu * mu + EPS_);
    const float hv2 = fmaxf((x - mu) * rs * g_r + be_r, 0.f);
    h_s[r] = hv2;
    hbf[r] = (ushort)bf16cvt(hv2);
    __syncthreads();
    return hv2;
  };

  float hv = 0.f;
  for (int t = 0; t < T_STEPS; ++t) {
    float xb;
    if (t == 0) {
      xb = area[r] + bh_r;                 // h==0: hb = zg
    } else {
      // Phase 1: hb = Wh.h via MFMA. B-fragments preloaded per 8-kk batch
      // (broadcast LDS reads, all lanes — lanes with c!=0 hold don't-care B;
      // only D col 0 (lanes c==0) is stored). Inner loop is pure
      // {global load -> MFMA}: the vmcnt ladder runs without lgkmcnt chains.
      f32x4 acc[4] = {{0.f,0.f,0.f,0.f},{0.f,0.f,0.f,0.f},
                      {0.f,0.f,0.f,0.f},{0.f,0.f,0.f,0.f}};
      uint4 bfr[8];
#pragma unroll
      for (int kk = 0; kk < 8; ++kk)
        bfr[kk] = *reinterpret_cast<const uint4*>(&hbf[kk*32 + gq*8]);
#pragma unroll
      for (int kk = 0; kk < 8; ++kk) {
        const short8 bv = __builtin_bit_cast(short8, bfr[kk]);
#pragma unroll
        for (int mt4 = 0; mt4 < 4; ++mt4) {
          const uint4 au = Wp[(size_t)((wave*4 + mt4)*16 + kk) * 64 + lane];
          acc[mt4] = __builtin_amdgcn_mfma_f32_16x16x32_bf16(
              __builtin_bit_cast(short8, au), bv, acc[mt4], 0,0,0);
        }
      }
#pragma unroll
      for (int kk = 0; kk < 8; ++kk)
        bfr[kk] = *reinterpret_cast<const uint4*>(&hbf[(kk + 8)*32 + gq*8]);
#pragma unroll
      for (int kk = 8; kk < 16; ++kk) {
        const short8 bv = __builtin_bit_cast(short8, bfr[kk - 8]);
#pragma unroll
        for (int mt4 = 0; mt4 < 4; ++mt4) {
          const uint4 au = Wp[(size_t)((wave*4 + mt4)*16 + kk) * 64 + lane];
          acc[mt4] = __builtin_amdgcn_mfma_f32_16x16x32_bf16(
              __builtin_bit_cast(short8, au), bv, acc[mt4], 0,0,0);
        }
      }
      if (c == 0) {
#pragma unroll
        for (int mt4 = 0; mt4 < 4; ++mt4)
          *reinterpret_cast<f32x4*>(&part[(wave*4 + mt4)*16 + gq*4]) = acc[mt4];
      }
      __syncthreads();                                   // B1
      xb = part[r] + area[(size_t)t * LDA + r] + bh_r;
    }

    // Phase 2: h = relu(LN(hb))
    hv = ln(xb);                                          // B2,B3

    // Phase 3: S_LOOP=2 fast-weight reads (A==0 at t=0 -> skip)
    if (t > 0) {
      for (int s = 0; s < 2; ++s) {
        // cc[sp] = ETA*lambda^(t-1-sp) * (hist[sp] . h)
        const float4 c0 = *reinterpret_cast<const float4*>(&h_s[lane * 8]);
        const float4 c1 = *reinterpret_cast<const float4*>(&h_s[lane * 8 + 4]);
        for (int sp = wave; sp < t; sp += 8) {
          const float* hr = &area[(size_t)sp * LDA];
          const float4 a0 = *reinterpret_cast<const float4*>(&hr[lane * 8]);
          const float4 a1 = *reinterpret_cast<const float4*>(&hr[lane * 8 + 4]);
          float d = c0.x*a0.x + c0.y*a0.y + c0.z*a0.z + c0.w*a0.w
                  + c1.x*a1.x + c1.y*a1.y + c1.z*a1.z + c1.w*a1.w;
#pragma unroll
          for (int off = 32; off; off >>= 1) d += __shfl_xor(d, off, 64);
          if (lane == 0) cc[sp] = ETA_ * lam_pow[t - 1 - sp] * d;
        }
        __syncthreads();                                  // B4
        // Ah from own-thread transposed bf16 history row: 4 x b128 + 32 fmaf
        float ah = 0.f;
#pragma unroll
        for (int q8 = 0; q8 < 4; ++q8) {
          const uint4 hw = *reinterpret_cast<const uint4*>(&histT[r][q8 * 8]);
          const uint w0 = hw.x, w1 = hw.y, w2 = hw.z, w3 = hw.w;
          ah = fmaf(cc[q8*8+0], __uint_as_float(w0 << 16),          ah);
          ah = fmaf(cc[q8*8+1], __uint_as_float(w0 & 0xFFFF0000u),  ah);
          ah = fmaf(cc[q8*8+2], __uint_as_float(w1 << 16),          ah);
          ah = fmaf(cc[q8*8+3], __uint_as_float(w1 & 0xFFFF0000u),  ah);
          ah = fmaf(cc[q8*8+4], __uint_as_float(w2 << 16),          ah);
          ah = fmaf(cc[q8*8+5], __uint_as_float(w2 & 0xFFFF0000u),  ah);
          ah = fmaf(cc[q8*8+6], __uint_as_float(w3 << 16),          ah);
          ah = fmaf(cc[q8*8+7], __uint_as_float(w3 & 0xFFFF0000u),  ah);
        }
        hv = ln(xb + ah);                                 // B5,B6
      }
    }

    // Phase 4: hist[t] := h (area row for dots; own histT row for Ah —
    // same-thread write/read, needs no barrier)
    if (t < T_STEPS - 1) {
      area[(size_t)t * LDA + r] = hv;
      histT[r][t] = (ushort)bf16cvt(hv);
    }
  }

  out[(size_t)b * DH + r] = hv;
}

extern "C" void kernel_launch(void* const* d_in, const int* in_sizes, int n_in,
                              void* d_out, int out_size, void* d_ws, size_t ws_size,
                              hipStream_t stream) {
  const float* z     = (const float*)d_in[0];  // [T,B,DG]
  const float* W_h   = (const float*)d_in[1];  // [DH,DH]
  const float* W_g   = (const float*)d_in[2];  // [DH,DG]
  const float* b_h   = (const float*)d_in[3];  // [DH]
  const float* gamma = (const float*)d_in[4];  // [DH]
  const float* beta  = (const float*)d_in[5];  // [DH]
  float* out = (float*)d_out;                  // [B,DH]

  uint4* Wp = (uint4*)d_ws;                    // 512 KB packed W_h

  pack_kernel<<<dim3(64), dim3(512), 0, stream>>>(W_h, Wp);
  rnn_kernel<<<dim3(BATCH), dim3(512), 0, stream>>>(Wp, z, W_g, b_h,
                                                    gamma, beta, out);
}

// Round 17
// 280.759 us; speedup vs baseline: 1.1431x; 1.0336x over previous
//
#include <hip/hip_runtime.h>

typedef __attribute__((ext_vector_type(8))) short short8;
typedef __attribute__((ext_vector_type(4))) float f32x4;

constexpr int T_STEPS = 32;
constexpr int BATCH   = 32;
constexpr int DG      = 256;
constexpr int DH      = 512;
constexpr int NHIST   = 31;
constexpr int LDH     = 528;    // area_bf row stride (u16): 1056 B, 16B-aligned
constexpr int LDT     = 40;     // histT row stride (u16): 80 B, 16B-aligned
constexpr float LAMBDA_ = 0.95f;
constexpr float ETA_    = 0.5f;
constexpr float EPS_    = 1e-5f;

__device__ __forceinline__ uint bf16cvt(float f) {
  uint u = __float_as_uint(f);
  return (u + 0x7FFFu + ((u >> 16) & 1u)) >> 16;
}
__device__ __forceinline__ uint pack2(float a, float b) {
  return bf16cvt(a) | (bf16cvt(b) << 16);
}
__device__ __forceinline__ float bf2f(ushort u) {
  return __uint_as_float(((uint)u) << 16);
}

// pack: W_h fp32 -> bf16 MFMA A-fragment layout.
// Wp[(mt*16+kk)*64 + lane] = uint4 of 8 bf16 =
//   W[mt*16 + (lane&15)][kk*32 + (lane>>4)*8 .. +8)
__global__ __launch_bounds__(512) void pack_kernel(
    const float* __restrict__ Wh, uint4* __restrict__ Wp) {
  const int f  = blockIdx.x * 512 + threadIdx.x;   // 0..32767
  const int lf = f & 63;
  const int kk = (f >> 6) & 15;
  const int mt = f >> 10;
  const int r  = mt * 16 + (lf & 15);
  const int k0 = kk * 32 + (lf >> 4) * 8;
  const float4 a = *reinterpret_cast<const float4*>(Wh + (size_t)r * DH + k0);
  const float4 b = *reinterpret_cast<const float4*>(Wh + (size_t)r * DH + k0 + 4);
  Wp[f] = make_uint4(pack2(a.x, a.y), pack2(a.z, a.w),
                     pack2(b.x, b.y), pack2(b.z, b.w));
}

// Serial recurrence: 32 self-contained blocks x 512 threads, one batch each.
// Per-CU L2 stream rate (~40 B/clk, measured rounds 3-16 + learn_hip m97) is
// the phase-1 ceiling, so REMOVE bytes from the stream: W kk=0,1 (64 KB)
// lives in LDS (separate ds_read pipe, copied once), and zg/history go bf16
// (area 68->33 KB) to make room. Stream is now 448 KB/step.
__global__ __launch_bounds__(512, 2) void rnn_kernel(
    const uint4* __restrict__ Wp, const float* __restrict__ z,
    const float* __restrict__ Wg, const float* __restrict__ bh,
    const float* __restrict__ g, const float* __restrict__ be,
    float* __restrict__ out) {
  __shared__ uint4  Wres[2 * 32 * 64];       // 64 KB: W kk=0,1 fragments
  __shared__ ushort area_bf[T_STEPS][LDH];   // 33 KB: zg[t] -> hist[t] (bf16)
  __shared__ ushort histT[DH][LDT];          // 40 KB: transposed history (Ah)
  __shared__ float  part[DH];
  __shared__ float  h_s[DH];
  __shared__ ushort hbf[DH];
  __shared__ float  red1[8], red2[8];
  __shared__ float  cc[NHIST + 1];
  __shared__ float  lam_pow[NHIST];

  const int tid  = threadIdx.x;            // 0..511
  const int lane = tid & 63;
  const int wave = tid >> 6;               // 0..7
  const int c    = lane & 15;              // mfma col
  const int gq   = lane >> 4;              // mfma k-group / row-quad
  const int b    = blockIdx.x;             // batch == block
  const int r    = tid;                    // owned row

  if (tid == 0) {
    float p = 1.f;
    for (int k = 0; k < NHIST; ++k) { lam_pow[k] = p; p *= LAMBDA_; }
  }
  if (tid < NHIST + 1) cc[tid] = 0.f;      // slots >= t stay 0 -> no Ah guards
  {                                         // zero own histT row (NaN guard)
    uint4 zz = make_uint4(0u, 0u, 0u, 0u);
#pragma unroll
    for (int i = 0; i < 5; ++i)
      reinterpret_cast<uint4*>(&histT[r][0])[i] = zz;
  }
  // ---- Copy resident W (kk=0,1 for all 32 M-tiles) into LDS ----
#pragma unroll
  for (int i2 = 0; i2 < 8; ++i2) {
    const int i  = i2 * 512 + tid;          // 0..4095
    const int mt = i >> 7, kkl = (i >> 6) & 1, ln2 = i & 63;
    Wres[i] = Wp[(size_t)(mt * 16 + kkl) * 64 + ln2];
  }

  // ---- Prologue: area_bf[t][:] = bf16(z_b @ Wg^T) (MFMA; cols = t) ----
#pragma unroll
  for (int mt4 = 0; mt4 < 4; ++mt4) {
    const int mt = wave * 4 + mt4;          // 32 M-tiles over DH=512
    f32x4 acc0 = {0.f,0.f,0.f,0.f}, acc1 = {0.f,0.f,0.f,0.f};
#pragma unroll
    for (int kk = 0; kk < 8; ++kk) {        // K = 256
      const int k0 = kk * 32 + gq * 8;
      const float4 a  = *reinterpret_cast<const float4*>(Wg + (size_t)(mt*16 + c) * DG + k0);
      const float4 a2 = *reinterpret_cast<const float4*>(Wg + (size_t)(mt*16 + c) * DG + k0 + 4);
      const uint4 afu = make_uint4(pack2(a.x,a.y), pack2(a.z,a.w),
                                   pack2(a2.x,a2.y), pack2(a2.z,a2.w));
      const float* zb0 = z + ((size_t)c        * BATCH + b) * DG + k0;  // t = c
      const float* zb1 = z + ((size_t)(16 + c) * BATCH + b) * DG + k0;  // t = 16+c
      const float4 b00 = *reinterpret_cast<const float4*>(zb0);
      const float4 b01 = *reinterpret_cast<const float4*>(zb0 + 4);
      const float4 b10 = *reinterpret_cast<const float4*>(zb1);
      const float4 b11 = *reinterpret_cast<const float4*>(zb1 + 4);
      const uint4 bf0 = make_uint4(pack2(b00.x,b00.y), pack2(b00.z,b00.w),
                                   pack2(b01.x,b01.y), pack2(b01.z,b01.w));
      const uint4 bf1 = make_uint4(pack2(b10.x,b10.y), pack2(b10.z,b10.w),
                                   pack2(b11.x,b11.y), pack2(b11.z,b11.w));
      acc0 = __builtin_amdgcn_mfma_f32_16x16x32_bf16(
          __builtin_bit_cast(short8, afu), __builtin_bit_cast(short8, bf0), acc0, 0,0,0);
      acc1 = __builtin_amdgcn_mfma_f32_16x16x32_bf16(
          __builtin_bit_cast(short8, afu), __builtin_bit_cast(short8, bf1), acc1, 0,0,0);
    }
    // D: col=lane&15 -> t, rows mt*16 + gq*4 + 0..3
    *reinterpret_cast<uint2*>(&area_bf[c][mt*16 + gq*4]) =
        make_uint2(pack2(acc0.x, acc0.y), pack2(acc0.z, acc0.w));
    *reinterpret_cast<uint2*>(&area_bf[16 + c][mt*16 + gq*4]) =
        make_uint2(pack2(acc1.x, acc1.y), pack2(acc1.z, acc1.w));
  }
  __syncthreads();

  const float bh_r = bh[r], g_r = g[r], be_r = be[r];

  // LayerNorm+ReLU over 512 thread-held scalars; 2 barriers; writes h_s+hbf.
  auto ln = [&](float x) -> float {
    float s1 = x, s2 = x * x;
#pragma unroll
    for (int off = 32; off; off >>= 1) {
      s1 += __shfl_xor(s1, off, 64);
      s2 += __shfl_xor(s2, off, 64);
    }
    if (lane == 0) { red1[wave] = s1; red2[wave] = s2; }
    __syncthreads();
    float a = 0.f, q = 0.f;
#pragma unroll
    for (int w2 = 0; w2 < 8; ++w2) { a += red1[w2]; q += red2[w2]; }
    const float mu = a * (1.f / DH);
    const float rs = rsqrtf(q * (1.f / DH) - mu * mu + EPS_);
    const float hv2 = fmaxf((x - mu) * rs * g_r + be_r, 0.f);
    h_s[r] = hv2;
    hbf[r] = (ushort)bf16cvt(hv2);
    __syncthreads();
    return hv2;
  };

  float hv = 0.f;
  for (int t = 0; t < T_STEPS; ++t) {
    float xb;
    if (t == 0) {
      xb = bf2f(area_bf[0][r]) + bh_r;     // h==0: hb = zg
    } else {
      // Phase 1: hb = Wh.h via MFMA. kk=0,1 from LDS (ds_read pipe, overlaps
      // the global stream); kk=2..15 streamed from L2 (448 KB/step).
      f32x4 acc[4] = {{0.f,0.f,0.f,0.f},{0.f,0.f,0.f,0.f},
                      {0.f,0.f,0.f,0.f},{0.f,0.f,0.f,0.f}};
      uint4 bfr[8];
#pragma unroll
      for (int kk = 0; kk < 8; ++kk)
        bfr[kk] = *reinterpret_cast<const uint4*>(&hbf[kk*32 + gq*8]);
      // resident kk=0,1
#pragma unroll
      for (int kk = 0; kk < 2; ++kk) {
        const short8 bv = __builtin_bit_cast(short8, bfr[kk]);
#pragma unroll
        for (int mt4 = 0; mt4 < 4; ++mt4) {
          const uint4 au = Wres[(size_t)((wave*4 + mt4)*2 + kk) * 64 + lane];
          acc[mt4] = __builtin_amdgcn_mfma_f32_16x16x32_bf16(
              __builtin_bit_cast(short8, au), bv, acc[mt4], 0,0,0);
        }
      }
      // streamed kk=2..7
#pragma unroll
      for (int kk = 2; kk < 8; ++kk) {
        const short8 bv = __builtin_bit_cast(short8, bfr[kk]);
#pragma unroll
        for (int mt4 = 0; mt4 < 4; ++mt4) {
          const uint4 au = Wp[(size_t)((wave*4 + mt4)*16 + kk) * 64 + lane];
          acc[mt4] = __builtin_amdgcn_mfma_f32_16x16x32_bf16(
              __builtin_bit_cast(short8, au), bv, acc[mt4], 0,0,0);
        }
      }
      // streamed kk=8..15
#pragma unroll
      for (int kk = 0; kk < 8; ++kk)
        bfr[kk] = *reinterpret_cast<const uint4*>(&hbf[(kk + 8)*32 + gq*8]);
#pragma unroll
      for (int kk = 8; kk < 16; ++kk) {
        const short8 bv = __builtin_bit_cast(short8, bfr[kk - 8]);
#pragma unroll
        for (int mt4 = 0; mt4 < 4; ++mt4) {
          const uint4 au = Wp[(size_t)((wave*4 + mt4)*16 + kk) * 64 + lane];
          acc[mt4] = __builtin_amdgcn_mfma_f32_16x16x32_bf16(
              __builtin_bit_cast(short8, au), bv, acc[mt4], 0,0,0);
        }
      }
      if (c == 0) {
#pragma unroll
        for (int mt4 = 0; mt4 < 4; ++mt4)
          *reinterpret_cast<f32x4*>(&part[(wave*4 + mt4)*16 + gq*4]) = acc[mt4];
      }
      __syncthreads();                                   // B1
      xb = part[r] + bf2f(area_bf[t][r]) + bh_r;
    }

    // Phase 2: h = relu(LN(hb))
    hv = ln(xb);                                          // B2,B3

    // Phase 3: S_LOOP=2 fast-weight reads (A==0 at t=0 -> skip)
    if (t > 0) {
      for (int s = 0; s < 2; ++s) {
        // cc[sp] = ETA*lambda^(t-1-sp) * (hist[sp] . h); bf16 rows, b128 reads
        const float4 c0 = *reinterpret_cast<const float4*>(&h_s[lane * 8]);
        const float4 c1 = *reinterpret_cast<const float4*>(&h_s[lane * 8 + 4]);
        for (int sp = wave; sp < t; sp += 8) {
          const uint4 hw = *reinterpret_cast<const uint4*>(&area_bf[sp][lane * 8]);
          float d;
          d =      __uint_as_float(hw.x << 16)          * c0.x;
          d = fmaf(__uint_as_float(hw.x & 0xFFFF0000u), c0.y, d);
          d = fmaf(__uint_as_float(hw.y << 16),         c0.z, d);
          d = fmaf(__uint_as_float(hw.y & 0xFFFF0000u), c0.w, d);
          d = fmaf(__uint_as_float(hw.z << 16),         c1.x, d);
          d = fmaf(__uint_as_float(hw.z & 0xFFFF0000u), c1.y, d);
          d = fmaf(__uint_as_float(hw.w << 16),         c1.z, d);
          d = fmaf(__uint_as_float(hw.w & 0xFFFF0000u), c1.w, d);
#pragma unroll
          for (int off = 32; off; off >>= 1) d += __shfl_xor(d, off, 64);
          if (lane == 0) cc[sp] = ETA_ * lam_pow[t - 1 - sp] * d;
        }
        __syncthreads();                                  // B4
        // Ah from own-thread transposed bf16 history row: 4 x b128 + 32 fmaf
        float ah = 0.f;
#pragma unroll
        for (int q8 = 0; q8 < 4; ++q8) {
          const uint4 hw = *reinterpret_cast<const uint4*>(&histT[r][q8 * 8]);
          const uint w0 = hw.x, w1 = hw.y, w2 = hw.z, w3 = hw.w;
          ah = fmaf(cc[q8*8+0], __uint_as_float(w0 << 16),          ah);
          ah = fmaf(cc[q8*8+1], __uint_as_float(w0 & 0xFFFF0000u),  ah);
          ah = fmaf(cc[q8*8+2], __uint_as_float(w1 << 16),          ah);
          ah = fmaf(cc[q8*8+3], __uint_as_float(w1 & 0xFFFF0000u),  ah);
          ah = fmaf(cc[q8*8+4], __uint_as_float(w2 << 16),          ah);
          ah = fmaf(cc[q8*8+5], __uint_as_float(w2 & 0xFFFF0000u),  ah);
          ah = fmaf(cc[q8*8+6], __uint_as_float(w3 << 16),          ah);
          ah = fmaf(cc[q8*8+7], __uint_as_float(w3 & 0xFFFF0000u),  ah);
        }
        hv = ln(xb + ah);                                 // B5,B6
      }
    }

    // Phase 4: hist[t] := h (area_bf row for dots; own histT row for Ah —
    // same-thread write/read, needs no barrier)
    if (t < T_STEPS - 1) {
      const ushort h16 = (ushort)bf16cvt(hv);
      area_bf[t][r] = h16;
      histT[r][t]   = h16;
    }
  }

  out[(size_t)b * DH + r] = hv;
}

extern "C" void kernel_launch(void* const* d_in, const int* in_sizes, int n_in,
                              void* d_out, int out_size, void* d_ws, size_t ws_size,
                              hipStream_t stream) {
  const float* z     = (const float*)d_in[0];  // [T,B,DG]
  const float* W_h   = (const float*)d_in[1];  // [DH,DH]
  const float* W_g   = (const float*)d_in[2];  // [DH,DG]
  const float* b_h   = (const float*)d_in[3];  // [DH]
  const float* gamma = (const float*)d_in[4];  // [DH]
  const float* beta  = (const float*)d_in[5];  // [DH]
  float* out = (float*)d_out;                  // [B,DH]

  uint4* Wp = (uint4*)d_ws;                    // 512 KB packed W_h

  pack_kernel<<<dim3(64), dim3(512), 0, stream>>>(W_h, Wp);
  rnn_kernel<<<dim3(BATCH), dim3(512), 0, stream>>>(Wp, z, W_g, b_h,
                                                    gamma, beta, out);
}